// Round 15
// baseline (126.404 us; speedup 1.0000x reference)
//
#include <hip/hip_runtime.h>
#include <math.h>

typedef short bf16x8 __attribute__((ext_vector_type(8)));
typedef short s16x2  __attribute__((ext_vector_type(2)));
typedef float f32x16 __attribute__((ext_vector_type(16)));
typedef float f32x4  __attribute__((ext_vector_type(4)));
typedef float f32x2  __attribute__((ext_vector_type(2)));
typedef unsigned int u32x4 __attribute__((ext_vector_type(4)));
typedef unsigned int u32x2 __attribute__((ext_vector_type(2)));

namespace {
constexpr int kNCont = 6, kNCat = 6, kNCategories = 100;
constexpr int kQ = 12, kD = 10, kHid = 20, kD0 = 10;
constexpr int kL1 = 30, kL2 = 20, kNPairs = 78;
constexpr int kMB = 64;           // batch tile per block (2 halves of 32)
constexpr int kBlock = 512;       // 8 waves
constexpr int kTB = 80;           // padded pair slots for tokb table
}

// Per-k-set ownership (partition of 0..11); pair counts 19/20/20/19.
__constant__ int cKset[12] = {11, 4, 1, 10, 5, 2, 9, 8, 0, 7, 6, 3};

union ABu { u32x4 u; bf16x8 s; unsigned int w[4]; unsigned short h[8]; };
union D16 { f32x16 v; f32x4 q[4]; f32x2 d[8]; float f[16]; };
union A12 { f32x2 d[6]; float f[12]; };

__device__ __forceinline__ unsigned int fu(float x) { return __float_as_uint(x); }
__device__ __forceinline__ unsigned short f2bf_rne(float v) {
    unsigned int x = fu(v);
    return (unsigned short)((x + 0x7FFFu + ((x >> 16) & 1u)) >> 16);
}
// pack two f32 to bf16x2 by truncation: low16 = hi(e0), high16 = hi(e1)
__device__ __forceinline__ unsigned int pack_trunc(float e0, float e1) {
    return __builtin_amdgcn_perm(fu(e1), fu(e0), 0x07060302u);
}
// pack two f32 to bf16x2 with RNE (for weight frags — matches verified chain)
__device__ __forceinline__ unsigned int pack_rne(float e0, float e1) {
    return (unsigned int)f2bf_rne(e0) | ((unsigned int)f2bf_rne(e1) << 16);
}
// one-instruction f32x2 -> packed bf16x2 (RNE): src0 -> low16, src1 -> high16
__device__ __forceinline__ unsigned int cvtpk(float lo, float hi) {
    unsigned int r;
    asm("v_cvt_pk_bf16_f32 %0, %1, %2" : "=v"(r) : "v"(lo), "v"(hi));
    return r;
}
// tau permutation (involution: tau(tau(x)) == x)
__device__ __forceinline__ int tauf(int x) {
    const int q2 = (x >> 2) & 3;
    return x + (q2 == 1 ? 4 : (q2 == 2 ? -4 : 0));
}

__global__ __launch_bounds__(kBlock, 2) void pin_main(
    const float* __restrict__ x_cont,
    const int*   __restrict__ x_cat,
    const float* __restrict__ exposure,
    const float* __restrict__ cont_W1,
    const float* __restrict__ cont_b1,
    const float* __restrict__ cont_W2,
    const float* __restrict__ cont_b2,
    const float* __restrict__ cat_tables,
    const float* __restrict__ tokens,  // [78,10]
    const float* __restrict__ sW1,     // [30,30]
    const float* __restrict__ sb1,     // [30]
    const float* __restrict__ sW2,     // [30,20]
    const float* __restrict__ sb2,     // [20]
    const float* __restrict__ sW3,     // [20]
    const float* __restrict__ sb3,     // [1]
    const float* __restrict__ out_w,   // [78]
    const float* __restrict__ out_b,   // [1]
    float* __restrict__ out)
{
    // E d0..7 packed bf16: [q][bb(64)][4 u32], 16B lane stride.
    __shared__ __align__(16) unsigned int EldsA[kQ * kMB * 4];  // 12288 B
    // E d8,d9 packed: [q][bb] one u32.
    __shared__ __align__(16) unsigned int EldsB[kQ * kMB];      // 3072 B
    // tokb in C-reg order [g*2+ih][p][4 f32]; first 5120 B double as the
    // bf16 frag-staging area fs[5][64][8 u16]. 10240 B.
    __shared__ __align__(16) float TokF[4 * 2 * kTB * 4];
    // out_w in LDS: pair-loop reads are in-order broadcast ds_read_b32.
    __shared__ float OW[kTB];
    __shared__ float etab[kMB];
    __shared__ float etaC;
    __shared__ unsigned int Zw[4];    // zero words for ihalf1 dummy reads

    const int tid   = threadIdx.x;
    const int lane  = tid & 63;
    const int b     = lane & 31;          // batch row within half / MFMA col n
    const int ihalf = lane >> 5;          // fragment k-half selector
    const int wv    = __builtin_amdgcn_readfirstlane((int)(tid >> 6)); // 0..7
    const int blockBase = blockIdx.x * kMB;

    if (tid < kMB) etab[tid] = 0.0f;
    if (tid == 0) { Zw[0] = 0u; Zw[1] = 0u; Zw[2] = 0u; Zw[3] = 0u; }
    if (tid < kNPairs) OW[tid] = out_w[tid];    // covered by bar3

    // ---- frag scatter-stage: threads build all frags in bf16 LDS frag
    // layout. u32 slot s (per frag): lane2 = s>>2, elem pair ep = s&3.
    // tid<256 -> frags 0,1,2 ; tid>=256 -> frags 3,4.
    {
        unsigned int* fsU32 = (unsigned int*)TokF;
        if (tid < 256) {
            const int s     = tid;
            const int lane2 = s >> 2;
            const int ep    = s & 3;
            const int bh    = lane2 >> 5;          // dest ihalf
            const int bb    = lane2 & 31;          // dest b
            const int cc    = tauf(bb);            // source col (sW1 frags)
            const int e0 = 2 * ep, e1 = e0 + 1;
            // f=0: wj0 — ih0: sW1 rows 0..7 ; ih1: rows 10..17 (col cc)
            {
                const int rb = bh ? 10 : 0;
                const float v0 = (cc < kL1) ? sW1[(rb + e0) * kL1 + cc] : 0.0f;
                const float v1 = (cc < kL1) ? sW1[(rb + e1) * kL1 + cc] : 0.0f;
                fsU32[0 * 256 + s] = pack_rne(v0, v1);
            }
            // f=1: wj1 — ih0 e=0,1 -> rows 8,9 ; e=2,3 -> rows 18,19 ; else 0
            {
                float v0 = 0.0f, v1 = 0.0f;
                if (bh == 0 && cc < kL1 && e0 < 4) {
                    v0 = sW1[((e0 < 2 ? 8 : 16) + e0) * kL1 + cc];
                    v1 = sW1[((e1 < 2 ? 8 : 16) + e1) * kL1 + cc];
                }
                fsU32[1 * 256 + s] = pack_rne(v0, v1);
            }
            // f=2: bf0 — sW2 rows k = bh*8+e (0..15), col bb
            {
                const float v0 = (bb < kL2) ? sW2[(bh * 8 + e0) * kL2 + bb] : 0.0f;
                const float v1 = (bb < kL2) ? sW2[(bh * 8 + e1) * kL2 + bb] : 0.0f;
                fsU32[2 * 256 + s] = pack_rne(v0, v1);
            }
        } else {
            const int s     = tid - 256;
            const int lane2 = s >> 2;
            const int ep    = s & 3;
            const int bh    = lane2 >> 5;
            const int bb    = lane2 & 31;
            const int cc    = tauf(bb);
            const int e0 = 2 * ep, e1 = e0 + 1;
            // f=3: bf1 — k = 16+bh*8+e (16..31); k==30 -> sb2; k==31 -> 0
            {
                const int k0 = 16 + bh * 8 + e0, k1 = k0 + 1;
                float v0 = 0.0f, v1 = 0.0f;
                if (bb < kL2) {
                    v0 = (k0 < kL1) ? sW2[k0 * kL2 + bb] : (k0 == 30 ? sb2[bb] : 0.0f);
                    v1 = (k1 < kL1) ? sW2[k1 * kL2 + bb] : (k1 == 30 ? sb2[bb] : 0.0f);
                }
                fsU32[3 * 256 + s] = pack_rne(v0, v1);
            }
            // f=4: tokbA — ih0: sW1 rows 20..27 ; ih1: e=0,1 -> rows 28,29,
            //       e=2 -> sb1 (cc<30) or 1.0 (cc==30), e>=3 -> 0
            {
                float v0 = 0.0f, v1 = 0.0f;
                if (bh == 0) {
                    if (cc < kL1) {
                        v0 = sW1[(20 + e0) * kL1 + cc];
                        v1 = sW1[(20 + e1) * kL1 + cc];
                    }
                } else {
                    if (e0 == 0) {
                        if (cc < kL1) { v0 = sW1[28 * kL1 + cc]; v1 = sW1[29 * kL1 + cc]; }
                    } else if (e0 == 2) {
                        v0 = (cc < kL1) ? sb1[cc] : (cc == 30 ? 1.0f : 0.0f);
                    }
                }
                fsU32[4 * 256 + s] = pack_rne(v0, v1);
            }
        }
    }
    __syncthreads();   // bar1: frag staging complete

    // ---- frag fetch: contiguous conflict-free b128 per lane ----
    const u32x4* fsV = (const u32x4*)TokF;    // 16B units: [f][lane]
    ABu wj0, wj1, bf0, bf1, a2;
    wj0.u = fsV[0 * 64 + lane];
    wj1.u = fsV[1 * 64 + lane];
    bf0.u = fsV[2 * 64 + lane];
    bf1.u = fsV[3 * 64 + lane];
    a2.u  = fsV[4 * 64 + lane];
    __syncthreads();   // bar2: frag reads done; fs region may be overwritten

    // ---- Phase A: 16 half-wave units.
    // Units 0..11 (waves 0-5): cont MLP q = unit%6, bhalf = unit/6.
    // Waves 6,7: cat gathers for bhalf 0/1 (3 feats per half-wave);
    // wave 7 also reduces etaConst. tokb on LIGHT waves 5,6,7. ----
    {
        const bool doTok = (wv >= 5);
        const int p = (wv - 5) * 32 + b;               // tokb slice pair idx
        f32x16 tc = {};
        if (doTok) {
            const int pc = min(p, kNPairs - 1);
            const float* tp = tokens + pc * kD0;
            const f32x4 ta = *(const f32x4*)(tp + ihalf * 6);
            const f32x4 tb = *(const f32x4*)(tp + 4);      // d4..7 (ih0 only)
            const unsigned int c01 = pack_trunc(ta.x, ta.y);
            const unsigned int c23 = pack_trunc(ta.z, ta.w);
            ABu b2;
            b2.w[0] = ihalf ? c23 : c01;                   // ih1 slot8,9 = d8,d9
            b2.w[1] = ihalf ? 0x00003F80u : c23;           // ih1 slot10 = 1.0
            b2.w[2] = ihalf ? 0u : pack_trunc(tb.x, tb.y);
            b2.w[3] = ihalf ? 0u : pack_trunc(tb.z, tb.w);
            tc = __builtin_amdgcn_mfma_f32_32x32x16_bf16(a2.s, b2.s, tc, 0, 0, 0);
        }

        if (wv < 6) {
            const int unit = (wv << 1) | ihalf;
            const int bh   = (unit >= 6) ? 1 : 0;
            const int q    = unit - 6 * bh;
            const int gbA  = blockBase + bh * 32 + b;

            // cont MLP (latency of tokb MFMA on wv==5 hides underneath)
            const float x = x_cont[gbA * kNCont + q];
            f32x2 E2[5];
            #pragma unroll
            for (int dd = 0; dd < 5; ++dd)
                E2[dd] = f32x2{cont_b2[q * kD + 2 * dd],
                               cont_b2[q * kD + 2 * dd + 1]};
            #pragma unroll 4
            for (int h = 0; h < kHid; ++h) {
                const float pre = fmaf(x, cont_W1[q * kHid + h],
                                       cont_b1[q * kHid + h]);
                const float hv  = fmaxf(pre, 0.0f);
                const f32x2 hv2 = {hv, hv};
                const float* w2 = cont_W2 + (q * kHid + h) * kD;
                #pragma unroll
                for (int dd = 0; dd < 5; ++dd)
                    E2[dd] = __builtin_elementwise_fma(
                        hv2, f32x2{w2[2 * dd], w2[2 * dd + 1]}, E2[dd]);
            }
            const int bb = bh * 32 + b;
            *(u32x4*)&EldsA[(q * kMB + bb) * 4] =
                u32x4{pack_trunc(E2[0].x, E2[0].y), pack_trunc(E2[1].x, E2[1].y),
                      pack_trunc(E2[2].x, E2[2].y), pack_trunc(E2[3].x, E2[3].y)};
            EldsB[q * kMB + bb] = pack_trunc(E2[4].x, E2[4].y);
        } else {
            const int bh  = wv - 6;
            const int gbA = blockBase + bh * 32 + b;
            const int c0  = ihalf * 3;
            int idxs[3];
            #pragma unroll
            for (int t = 0; t < 3; ++t)
                idxs[t] = x_cat[gbA * kNCat + c0 + t];   // issue all idx loads
            const int bb = bh * 32 + b;
            #pragma unroll
            for (int t = 0; t < 3; ++t) {
                const int c = c0 + t;
                const int q = kNCont + c;
                const float* src = cat_tables + (c * kNCategories + idxs[t]) * kD;
                f32x2 E2[5];
                #pragma unroll
                for (int dd = 0; dd < 5; ++dd)
                    E2[dd] = f32x2{src[2 * dd], src[2 * dd + 1]};
                *(u32x4*)&EldsA[(q * kMB + bb) * 4] =
                    u32x4{pack_trunc(E2[0].x, E2[0].y), pack_trunc(E2[1].x, E2[1].y),
                          pack_trunc(E2[2].x, E2[2].y), pack_trunc(E2[3].x, E2[3].y)};
                EldsB[q * kMB + bb] = pack_trunc(E2[4].x, E2[4].y);
            }
            if (wv == 7) {
                // etaConst = out_b + sb3/6 * sum(out_w)
                float v = (lane < kNPairs) ? out_w[lane] : 0.0f;
                if (lane < kNPairs - 64) v += out_w[64 + lane];
                v += __shfl_xor(v, 1, 64);
                v += __shfl_xor(v, 2, 64);
                v += __shfl_xor(v, 4, 64);
                v += __shfl_xor(v, 8, 64);
                v += __shfl_xor(v, 16, 64);
                v += __shfl_xor(v, 32, 64);
                if (lane == 0) etaC = out_b[0] + sb3[0] * (1.0f / 6.0f) * v;
            }
        }

        // store tokb slice (16B lane stride, conflict-free)
        if (doTok && p < kNPairs) {
            D16 u; u.v = tc;
            #pragma unroll
            for (int g = 0; g < 4; ++g)
                *(f32x4*)&TokF[(g * 2 + ihalf) * (kTB * 4) + p * 4] = u.q[g];
        }
    }
    __syncthreads();   // bar3: E table + Tok + OW ready

    // ---- Phase B: DUAL-HALF fused pair loop.
    // Wave = (k-set = wv&3, j-parity = wv>>2). Each iteration handles pair
    // (j,k) for BOTH batch halves, sharing the tok C-init (dc) and OW[p].
    // Pack stage: f32 pk_max relu then v_cvt_pk_bf16_f32 (16 VALU/half,
    // was 24 perm+pk_max_i16; shortens d1->d2 dependent VALU run). ----
    A12 accA, accB;
    #pragma unroll
    for (int h = 0; h < 6; ++h) { accA.d[h] = f32x2{0.0f, 0.0f};
                                  accB.d[h] = f32x2{0.0f, 0.0f}; }

    const int kw   = wv & 3;
    const int jpar = wv >> 2;
    const unsigned int* e0base0 = EldsA + b * 4;              // half 0
    const unsigned int* e0base1 = EldsA + (32 + b) * 4;       // half 1
    const unsigned int* e1base0 = ihalf ? Zw : (EldsB + b);
    const unsigned int* e1base1 = ihalf ? Zw : (EldsB + 32 + b);
    const float* tokBase = TokF + ihalf * (kTB * 4);
    const int e0step = ihalf ? 0 : 2 * (kMB * 4);             // j += 2
    const int e1step = ihalf ? 0 : 2 * kMB;

    #pragma unroll 1
    for (int ki = 0; ki < 3; ++ki) {
        const int k = __builtin_amdgcn_readfirstlane(cKset[kw * 3 + ki]);
        const unsigned int ekb0 = *(e1base0 + (ihalf ? 0 : k * kMB));
        const unsigned int ekb1 = *(e1base1 + (ihalf ? 0 : k * kMB));
        const unsigned int* pj0A = e0base0 + (ihalf ? k : jpar) * (kMB * 4);
        const unsigned int* pj0B = e0base1 + (ihalf ? k : jpar) * (kMB * 4);
        const unsigned int* pj1A = e1base0 + (ihalf ? 0 : jpar * kMB);
        const unsigned int* pj1B = e1base1 + (ihalf ? 0 : jpar * kMB);

        int j = jpar;
        int p = jpar ? (11 + k) : k;       // p(j) at j = jpar
        #pragma unroll 1
        for (; j <= k; ) {
            // shared tok C-init (broadcast; serves BOTH halves)
            const float* tp2 = tokBase + p * 4;
            D16 dc;
            dc.q[0] = *(const f32x4*)(tp2);
            dc.q[1] = *(const f32x4*)(tp2 + 2 * kTB * 4);
            dc.q[2] = *(const f32x4*)(tp2 + 4 * kTB * 4);
            dc.q[3] = *(const f32x4*)(tp2 + 6 * kTB * 4);

            // e-frags for both halves
            ABu e0A; e0A.u = *(const u32x4*)pj0A;
            ABu e0B; e0B.u = *(const u32x4*)pj0B;
            const unsigned int ejbA = *pj1A;
            const unsigned int ejbB = *pj1B;
            ABu e1A; e1A.u = u32x4{ejbA, ekb0, 0u, 0u};
            ABu e1B; e1B.u = u32x4{ejbB, ekb1, 0u, 0u};

            const float wp = OW[p];                 // broadcast ds_read (in-order)
            const f32x2 wp2 = {wp, wp};
            const f32x2 z2 = {};

            // two independent layer-1 chains
            f32x16 d1a = dc.v;
            d1a = __builtin_amdgcn_mfma_f32_32x32x16_bf16(wj0.s, e0A.s, d1a, 0, 0, 0);
            d1a = __builtin_amdgcn_mfma_f32_32x32x16_bf16(wj1.s, e1A.s, d1a, 0, 0, 0);
            f32x16 d1b = dc.v;
            d1b = __builtin_amdgcn_mfma_f32_32x32x16_bf16(wj0.s, e0B.s, d1b, 0, 0, 0);
            d1b = __builtin_amdgcn_mfma_f32_32x32x16_bf16(wj1.s, e1B.s, d1b, 0, 0, 0);

            // finish half 0: f32 relu -> cvt_pk -> d2 -> weighted acc
            {
                D16 t; t.v = d1a;
                f32x2 r0 = __builtin_elementwise_max(t.d[0], z2);
                f32x2 r1 = __builtin_elementwise_max(t.d[1], z2);
                f32x2 r2 = __builtin_elementwise_max(t.d[2], z2);
                f32x2 r3 = __builtin_elementwise_max(t.d[3], z2);
                f32x2 r4 = __builtin_elementwise_max(t.d[4], z2);
                f32x2 r5 = __builtin_elementwise_max(t.d[5], z2);
                f32x2 r6 = __builtin_elementwise_max(t.d[6], z2);
                f32x2 r7 = __builtin_elementwise_max(t.d[7], z2);
                ABu hf0, hf1;
                hf0.w[0] = cvtpk(r0.x, r0.y);
                hf0.w[1] = cvtpk(r1.x, r1.y);
                hf0.w[2] = cvtpk(r2.x, r2.y);
                hf0.w[3] = cvtpk(r3.x, r3.y);
                hf1.w[0] = cvtpk(r4.x, r4.y);
                hf1.w[1] = cvtpk(r5.x, r5.y);
                hf1.w[2] = cvtpk(r6.x, r6.y);
                hf1.w[3] = cvtpk(r7.x, r7.y);
                f32x16 d2 = {};
                d2 = __builtin_amdgcn_mfma_f32_32x32x16_bf16(bf0.s, hf0.s, d2, 0, 0, 0);
                d2 = __builtin_amdgcn_mfma_f32_32x32x16_bf16(bf1.s, hf1.s, d2, 0, 0, 0);
                D16 r2u; r2u.v = d2;
                #pragma unroll
                for (int h = 0; h < 6; ++h) {
                    const f32x2 rr = __builtin_elementwise_max(r2u.d[h], z2);
                    accA.d[h] = __builtin_elementwise_fma(rr, wp2, accA.d[h]);
                }
            }
            // finish half 1
            {
                D16 t; t.v = d1b;
                f32x2 r0 = __builtin_elementwise_max(t.d[0], z2);
                f32x2 r1 = __builtin_elementwise_max(t.d[1], z2);
                f32x2 r2 = __builtin_elementwise_max(t.d[2], z2);
                f32x2 r3 = __builtin_elementwise_max(t.d[3], z2);
                f32x2 r4 = __builtin_elementwise_max(t.d[4], z2);
                f32x2 r5 = __builtin_elementwise_max(t.d[5], z2);
                f32x2 r6 = __builtin_elementwise_max(t.d[6], z2);
                f32x2 r7 = __builtin_elementwise_max(t.d[7], z2);
                ABu hf0, hf1;
                hf0.w[0] = cvtpk(r0.x, r0.y);
                hf0.w[1] = cvtpk(r1.x, r1.y);
                hf0.w[2] = cvtpk(r2.x, r2.y);
                hf0.w[3] = cvtpk(r3.x, r3.y);
                hf1.w[0] = cvtpk(r4.x, r4.y);
                hf1.w[1] = cvtpk(r5.x, r5.y);
                hf1.w[2] = cvtpk(r6.x, r6.y);
                hf1.w[3] = cvtpk(r7.x, r7.y);
                f32x16 d2 = {};
                d2 = __builtin_amdgcn_mfma_f32_32x32x16_bf16(bf0.s, hf0.s, d2, 0, 0, 0);
                d2 = __builtin_amdgcn_mfma_f32_32x32x16_bf16(bf1.s, hf1.s, d2, 0, 0, 0);
                D16 r2u; r2u.v = d2;
                #pragma unroll
                for (int h = 0; h < 6; ++h) {
                    const f32x2 rr = __builtin_elementwise_max(r2u.d[h], z2);
                    accB.d[h] = __builtin_elementwise_fma(rr, wp2, accB.d[h]);
                }
            }

            // advance j += 2 (p(j+2)-p(j) = 21-2j)
            p += 21 - 2 * j;
            j += 2;
            pj0A += e0step; pj0B += e0step;
            pj1A += e1step; pj1B += e1step;
        }
    }

    // ---- epilogue: eta[bb] = (1/6)*sum_r sW3[o_r]*acc[r], both halves ----
    float etaA = 0.0f, etaB = 0.0f;
    if (ihalf == 0) {       // r=0..11 -> o = 0..3, 8..11, 16..19
        #pragma unroll
        for (int r = 0; r < 12; ++r) {
            const float w3 = sW3[(r & 3) + 8 * (r >> 2)];
            etaA = fmaf(accA.f[r], w3, etaA);
            etaB = fmaf(accB.f[r], w3, etaB);
        }
    } else {                // r=0..7 -> o = 4..7, 12..15
        #pragma unroll
        for (int r = 0; r < 8; ++r) {
            const float w3 = sW3[(r & 3) + 8 * (r >> 2) + 4];
            etaA = fmaf(accA.f[r], w3, etaA);
            etaB = fmaf(accB.f[r], w3, etaB);
        }
    }
    etaA += __shfl_xor(etaA, 32, 64);   // combine o-halves
    etaB += __shfl_xor(etaB, 32, 64);
    if (ihalf == 0) {
        atomicAdd(&etab[b], etaA);
        atomicAdd(&etab[32 + b], etaB);
    }
    __syncthreads();

    if (tid < kMB) {
        float eta = etab[tid] * (1.0f / 6.0f) + etaC;
        eta = fminf(fmaxf(eta, -20.0f), 20.0f);
        const int ob = blockBase + tid;
        out[ob] = __expf(eta) * exposure[ob];
    }
}

extern "C" void kernel_launch(void* const* d_in, const int* in_sizes, int n_in,
                              void* d_out, int out_size, void* d_ws, size_t ws_size,
                              hipStream_t stream) {
    (void)n_in; (void)out_size; (void)d_ws; (void)ws_size;
    const float* x_cont     = (const float*)d_in[0];
    const int*   x_cat      = (const int*)  d_in[1];
    const float* exposure   = (const float*)d_in[2];
    const float* cont_W1    = (const float*)d_in[3];
    const float* cont_b1    = (const float*)d_in[4];
    const float* cont_W2    = (const float*)d_in[5];
    const float* cont_b2    = (const float*)d_in[6];
    const float* cat_tables = (const float*)d_in[7];
    const float* tokens     = (const float*)d_in[8];
    const float* sW1        = (const float*)d_in[9];
    const float* sb1        = (const float*)d_in[10];
    const float* sW2        = (const float*)d_in[11];
    const float* sb2        = (const float*)d_in[12];
    const float* sW3        = (const float*)d_in[13];
    const float* sb3        = (const float*)d_in[14];
    const float* out_w      = (const float*)d_in[15];
    const float* out_b      = (const float*)d_in[16];

    const int B = in_sizes[2];        // exposure is [B]
    pin_main<<<B / kMB, kBlock, 0, stream>>>(
        x_cont, x_cat, exposure, cont_W1, cont_b1, cont_W2, cont_b2,
        cat_tables, tokens, sW1, sb1, sW2, sb2, sW3, sb3, out_w, out_b,
        (float*)d_out);
}

// Round 16
// 119.223 us; speedup vs baseline: 1.0602x; 1.0602x over previous
//
#include <hip/hip_runtime.h>
#include <math.h>

typedef short bf16x8 __attribute__((ext_vector_type(8)));
typedef short s16x2  __attribute__((ext_vector_type(2)));
typedef float f32x16 __attribute__((ext_vector_type(16)));
typedef float f32x4  __attribute__((ext_vector_type(4)));
typedef float f32x2  __attribute__((ext_vector_type(2)));
typedef unsigned int u32x4 __attribute__((ext_vector_type(4)));
typedef unsigned int u32x2 __attribute__((ext_vector_type(2)));

namespace {
constexpr int kNCont = 6, kNCat = 6, kNCategories = 100;
constexpr int kQ = 12, kD = 10, kHid = 20, kD0 = 10;
constexpr int kL1 = 30, kL2 = 20, kNPairs = 78;
constexpr int kMB = 64;           // batch tile per block (2 halves of 32)
constexpr int kBlock = 512;       // 8 waves
constexpr int kTB = 80;           // padded pair slots for tokb table
}

// Per-k-set ownership (partition of 0..11); pair counts 19/20/20/19.
__constant__ int cKset[12] = {11, 4, 1, 10, 5, 2, 9, 8, 0, 7, 6, 3};

union ABu { u32x4 u; bf16x8 s; unsigned int w[4]; unsigned short h[8]; };
union D16 { f32x16 v; f32x4 q[4]; f32x2 d[8]; float f[16]; };
union A12 { f32x2 d[6]; float f[12]; };

__device__ __forceinline__ unsigned int fu(float x) { return __float_as_uint(x); }
__device__ __forceinline__ unsigned short f2bf_rne(float v) {
    unsigned int x = fu(v);
    return (unsigned short)((x + 0x7FFFu + ((x >> 16) & 1u)) >> 16);
}
// pack two f32 to bf16x2 by truncation: low16 = hi(e0), high16 = hi(e1)
__device__ __forceinline__ unsigned int pack_trunc(float e0, float e1) {
    return __builtin_amdgcn_perm(fu(e1), fu(e0), 0x07060302u);
}
// pack two f32 to bf16x2 with RNE (for weight frags — matches verified chain)
__device__ __forceinline__ unsigned int pack_rne(float e0, float e1) {
    return (unsigned int)f2bf_rne(e0) | ((unsigned int)f2bf_rne(e1) << 16);
}
// packed relu on a u32 holding 2 bf16: max_i16(x,0) == relu per bf16 half
__device__ __forceinline__ unsigned int pk_relu(unsigned int w) {
    s16x2 v; __builtin_memcpy(&v, &w, 4);
    const s16x2 z = {0, 0};
    v = __builtin_elementwise_max(v, z);
    unsigned int r; __builtin_memcpy(&r, &v, 4);
    return r;
}
// tau permutation (involution: tau(tau(x)) == x)
__device__ __forceinline__ int tauf(int x) {
    const int q2 = (x >> 2) & 3;
    return x + (q2 == 1 ? 4 : (q2 == 2 ? -4 : 0));
}

__global__ __launch_bounds__(kBlock, 2) void pin_main(
    const float* __restrict__ x_cont,
    const int*   __restrict__ x_cat,
    const float* __restrict__ exposure,
    const float* __restrict__ cont_W1,
    const float* __restrict__ cont_b1,
    const float* __restrict__ cont_W2,
    const float* __restrict__ cont_b2,
    const float* __restrict__ cat_tables,
    const float* __restrict__ tokens,  // [78,10]
    const float* __restrict__ sW1,     // [30,30]
    const float* __restrict__ sb1,     // [30]
    const float* __restrict__ sW2,     // [30,20]
    const float* __restrict__ sb2,     // [20]
    const float* __restrict__ sW3,     // [20]
    const float* __restrict__ sb3,     // [1]
    const float* __restrict__ out_w,   // [78]
    const float* __restrict__ out_b,   // [1]
    float* __restrict__ out)
{
    // E d0..7 packed bf16: [q][bb(64)][4 u32], 16B lane stride.
    __shared__ __align__(16) unsigned int EldsA[kQ * kMB * 4];  // 12288 B
    // E d8,d9 packed: [q][bb] one u32.
    __shared__ __align__(16) unsigned int EldsB[kQ * kMB];      // 3072 B
    // tokb in C-reg order [g*2+ih][p][4 f32]; first 5120 B double as the
    // bf16 frag-staging area fs[5][64][8 u16]. 10240 B.
    __shared__ __align__(16) float TokF[4 * 2 * kTB * 4];
    __shared__ float etab[kMB];
    __shared__ float etaC;
    __shared__ unsigned int Zw[4];    // zero words for ihalf1 dummy reads

    const int tid   = threadIdx.x;
    const int lane  = tid & 63;
    const int b     = lane & 31;          // batch row within half / MFMA col n
    const int ihalf = lane >> 5;          // fragment k-half selector
    const int wv    = __builtin_amdgcn_readfirstlane((int)(tid >> 6)); // 0..7
    const int blockBase = blockIdx.x * kMB;

    if (tid < kMB) etab[tid] = 0.0f;
    if (tid == 0) { Zw[0] = 0u; Zw[1] = 0u; Zw[2] = 0u; Zw[3] = 0u; }

    // ---- frag scatter-stage: threads build all frags in bf16 LDS frag
    // layout. u32 slot s (per frag): lane2 = s>>2, elem pair ep = s&3.
    // tid<256 -> frags 0,1,2 ; tid>=256 -> frags 3,4.
    {
        unsigned int* fsU32 = (unsigned int*)TokF;
        if (tid < 256) {
            const int s     = tid;
            const int lane2 = s >> 2;
            const int ep    = s & 3;
            const int bh    = lane2 >> 5;          // dest ihalf
            const int bb    = lane2 & 31;          // dest b
            const int cc    = tauf(bb);            // source col (sW1 frags)
            const int e0 = 2 * ep, e1 = e0 + 1;
            // f=0: wj0 — ih0: sW1 rows 0..7 ; ih1: rows 10..17 (col cc)
            {
                const int rb = bh ? 10 : 0;
                const float v0 = (cc < kL1) ? sW1[(rb + e0) * kL1 + cc] : 0.0f;
                const float v1 = (cc < kL1) ? sW1[(rb + e1) * kL1 + cc] : 0.0f;
                fsU32[0 * 256 + s] = pack_rne(v0, v1);
            }
            // f=1: wj1 — ih0 e=0,1 -> rows 8,9 ; e=2,3 -> rows 18,19 ; else 0
            {
                float v0 = 0.0f, v1 = 0.0f;
                if (bh == 0 && cc < kL1 && e0 < 4) {
                    v0 = sW1[((e0 < 2 ? 8 : 16) + e0) * kL1 + cc];
                    v1 = sW1[((e1 < 2 ? 8 : 16) + e1) * kL1 + cc];
                }
                fsU32[1 * 256 + s] = pack_rne(v0, v1);
            }
            // f=2: bf0 — sW2 rows k = bh*8+e (0..15), col bb
            {
                const float v0 = (bb < kL2) ? sW2[(bh * 8 + e0) * kL2 + bb] : 0.0f;
                const float v1 = (bb < kL2) ? sW2[(bh * 8 + e1) * kL2 + bb] : 0.0f;
                fsU32[2 * 256 + s] = pack_rne(v0, v1);
            }
        } else {
            const int s     = tid - 256;
            const int lane2 = s >> 2;
            const int ep    = s & 3;
            const int bh    = lane2 >> 5;
            const int bb    = lane2 & 31;
            const int cc    = tauf(bb);
            const int e0 = 2 * ep, e1 = e0 + 1;
            // f=3: bf1 — k = 16+bh*8+e (16..31); k==30 -> sb2; k==31 -> 0
            {
                const int k0 = 16 + bh * 8 + e0, k1 = k0 + 1;
                float v0 = 0.0f, v1 = 0.0f;
                if (bb < kL2) {
                    v0 = (k0 < kL1) ? sW2[k0 * kL2 + bb] : (k0 == 30 ? sb2[bb] : 0.0f);
                    v1 = (k1 < kL1) ? sW2[k1 * kL2 + bb] : (k1 == 30 ? sb2[bb] : 0.0f);
                }
                fsU32[3 * 256 + s] = pack_rne(v0, v1);
            }
            // f=4: tokbA — ih0: sW1 rows 20..27 ; ih1: e=0,1 -> rows 28,29,
            //       e=2 -> sb1 (cc<30) or 1.0 (cc==30), e>=3 -> 0
            {
                float v0 = 0.0f, v1 = 0.0f;
                if (bh == 0) {
                    if (cc < kL1) {
                        v0 = sW1[(20 + e0) * kL1 + cc];
                        v1 = sW1[(20 + e1) * kL1 + cc];
                    }
                } else {
                    if (e0 == 0) {
                        if (cc < kL1) { v0 = sW1[28 * kL1 + cc]; v1 = sW1[29 * kL1 + cc]; }
                    } else if (e0 == 2) {
                        v0 = (cc < kL1) ? sb1[cc] : (cc == 30 ? 1.0f : 0.0f);
                    }
                }
                fsU32[4 * 256 + s] = pack_rne(v0, v1);
            }
        }
    }
    __syncthreads();   // bar1: frag staging complete

    // ---- frag fetch: contiguous conflict-free b128 per lane ----
    const u32x4* fsV = (const u32x4*)TokF;    // 16B units: [f][lane]
    ABu wj0, wj1, bf0, bf1, a2;
    wj0.u = fsV[0 * 64 + lane];
    wj1.u = fsV[1 * 64 + lane];
    bf0.u = fsV[2 * 64 + lane];
    bf1.u = fsV[3 * 64 + lane];
    a2.u  = fsV[4 * 64 + lane];
    __syncthreads();   // bar2: frag reads done; fs region may be overwritten

    // ---- Phase A: 16 half-wave units.
    // Units 0..11 (waves 0-5): cont MLP q = unit%6, bhalf = unit/6.
    // Waves 6,7: cat gathers for bhalf 0/1 (3 feats per half-wave);
    // wave 7 also reduces etaConst. Waves 0-2 additionally build tokb. ----
    if (wv < 6) {
        const int unit = (wv << 1) | ihalf;
        const int bh   = (unit >= 6) ? 1 : 0;
        const int q    = unit - 6 * bh;
        const int gbA  = blockBase + bh * 32 + b;

        f32x16 tc = {};
        const bool doTok = (wv < 3);
        const int p = wv * 32 + b;
        if (doTok) {
            const int pc = min(p, kNPairs - 1);
            const float* tp = tokens + pc * kD0;
            const f32x4 ta = *(const f32x4*)(tp + ihalf * 6);
            const f32x4 tb = *(const f32x4*)(tp + 4);      // d4..7 (ih0 only)
            const unsigned int c01 = pack_trunc(ta.x, ta.y);
            const unsigned int c23 = pack_trunc(ta.z, ta.w);
            ABu b2;
            b2.w[0] = ihalf ? c23 : c01;                   // ih1 slot8,9 = d8,d9
            b2.w[1] = ihalf ? 0x00003F80u : c23;           // ih1 slot10 = 1.0
            b2.w[2] = ihalf ? 0u : pack_trunc(tb.x, tb.y);
            b2.w[3] = ihalf ? 0u : pack_trunc(tb.z, tb.w);
            tc = __builtin_amdgcn_mfma_f32_32x32x16_bf16(a2.s, b2.s, tc, 0, 0, 0);
        }

        // cont MLP (latency of tokb MFMA hides underneath)
        const float x = x_cont[gbA * kNCont + q];
        f32x2 E2[5];
        #pragma unroll
        for (int dd = 0; dd < 5; ++dd)
            E2[dd] = f32x2{cont_b2[q * kD + 2 * dd], cont_b2[q * kD + 2 * dd + 1]};
        #pragma unroll 4
        for (int h = 0; h < kHid; ++h) {
            const float pre = fmaf(x, cont_W1[q * kHid + h], cont_b1[q * kHid + h]);
            const float hv  = fmaxf(pre, 0.0f);
            const f32x2 hv2 = {hv, hv};
            const float* w2 = cont_W2 + (q * kHid + h) * kD;
            #pragma unroll
            for (int dd = 0; dd < 5; ++dd)
                E2[dd] = __builtin_elementwise_fma(
                    hv2, f32x2{w2[2 * dd], w2[2 * dd + 1]}, E2[dd]);
        }
        const int bb = bh * 32 + b;
        *(u32x4*)&EldsA[(q * kMB + bb) * 4] =
            u32x4{pack_trunc(E2[0].x, E2[0].y), pack_trunc(E2[1].x, E2[1].y),
                  pack_trunc(E2[2].x, E2[2].y), pack_trunc(E2[3].x, E2[3].y)};
        EldsB[q * kMB + bb] = pack_trunc(E2[4].x, E2[4].y);

        // store tokb slice (16B lane stride, conflict-free)
        if (doTok && p < kNPairs) {
            D16 u; u.v = tc;
            #pragma unroll
            for (int g = 0; g < 4; ++g)
                *(f32x4*)&TokF[(g * 2 + ihalf) * (kTB * 4) + p * 4] = u.q[g];
        }
    } else {
        const int bh  = wv - 6;
        const int gbA = blockBase + bh * 32 + b;
        const int c0  = ihalf * 3;
        int idxs[3];
        #pragma unroll
        for (int t = 0; t < 3; ++t)
            idxs[t] = x_cat[gbA * kNCat + c0 + t];       // issue all idx loads
        const int bb = bh * 32 + b;
        #pragma unroll
        for (int t = 0; t < 3; ++t) {
            const int c = c0 + t;
            const int q = kNCont + c;
            const float* src = cat_tables + (c * kNCategories + idxs[t]) * kD;
            f32x2 E2[5];
            #pragma unroll
            for (int dd = 0; dd < 5; ++dd)
                E2[dd] = f32x2{src[2 * dd], src[2 * dd + 1]};
            *(u32x4*)&EldsA[(q * kMB + bb) * 4] =
                u32x4{pack_trunc(E2[0].x, E2[0].y), pack_trunc(E2[1].x, E2[1].y),
                      pack_trunc(E2[2].x, E2[2].y), pack_trunc(E2[3].x, E2[3].y)};
            EldsB[q * kMB + bb] = pack_trunc(E2[4].x, E2[4].y);
        }
        if (wv == 7) {
            // etaConst = out_b + sb3/6 * sum(out_w)
            float v = (lane < kNPairs) ? out_w[lane] : 0.0f;
            if (lane < kNPairs - 64) v += out_w[64 + lane];
            v += __shfl_xor(v, 1, 64);
            v += __shfl_xor(v, 2, 64);
            v += __shfl_xor(v, 4, 64);
            v += __shfl_xor(v, 8, 64);
            v += __shfl_xor(v, 16, 64);
            v += __shfl_xor(v, 32, 64);
            if (lane == 0) etaC = out_b[0] + sb3[0] * (1.0f / 6.0f) * v;
        }
    }
    __syncthreads();   // bar3: E table + Tok ready

    // ---- Phase B: DUAL-HALF fused pair loop.
    // Wave = (k-set = wv&3, j-parity = wv>>2). Each iteration handles pair
    // (j,k) for BOTH batch halves, sharing the tok C-init (dc) and out_w[p]
    // — halves the dominant LDS traffic and gives two independent
    // d1->pack->d2 chains per iteration (forced ILP). ----
    A12 accA, accB;
    #pragma unroll
    for (int h = 0; h < 6; ++h) { accA.d[h] = f32x2{0.0f, 0.0f};
                                  accB.d[h] = f32x2{0.0f, 0.0f}; }

    const int kw   = wv & 3;
    const int jpar = wv >> 2;
    const unsigned int* e0base0 = EldsA + b * 4;              // half 0
    const unsigned int* e0base1 = EldsA + (32 + b) * 4;       // half 1
    const unsigned int* e1base0 = ihalf ? Zw : (EldsB + b);
    const unsigned int* e1base1 = ihalf ? Zw : (EldsB + 32 + b);
    const float* tokBase = TokF + ihalf * (kTB * 4);
    const int e0step = ihalf ? 0 : 2 * (kMB * 4);             // j += 2
    const int e1step = ihalf ? 0 : 2 * kMB;

    #pragma unroll 1
    for (int ki = 0; ki < 3; ++ki) {
        const int k = __builtin_amdgcn_readfirstlane(cKset[kw * 3 + ki]);
        const unsigned int ekb0 = *(e1base0 + (ihalf ? 0 : k * kMB));
        const unsigned int ekb1 = *(e1base1 + (ihalf ? 0 : k * kMB));
        const unsigned int* pj0A = e0base0 + (ihalf ? k : jpar) * (kMB * 4);
        const unsigned int* pj0B = e0base1 + (ihalf ? k : jpar) * (kMB * 4);
        const unsigned int* pj1A = e1base0 + (ihalf ? 0 : jpar * kMB);
        const unsigned int* pj1B = e1base1 + (ihalf ? 0 : jpar * kMB);

        int j = jpar;
        int p = jpar ? (11 + k) : k;       // p(j) at j = jpar
        #pragma unroll 1
        for (; j <= k; ) {
            // shared tok C-init (broadcast; serves BOTH halves)
            const float* tp2 = tokBase + p * 4;
            D16 dc;
            dc.q[0] = *(const f32x4*)(tp2);
            dc.q[1] = *(const f32x4*)(tp2 + 2 * kTB * 4);
            dc.q[2] = *(const f32x4*)(tp2 + 4 * kTB * 4);
            dc.q[3] = *(const f32x4*)(tp2 + 6 * kTB * 4);

            // e-frags for both halves
            ABu e0A; e0A.u = *(const u32x4*)pj0A;
            ABu e0B; e0B.u = *(const u32x4*)pj0B;
            const unsigned int ejbA = *pj1A;
            const unsigned int ejbB = *pj1B;
            ABu e1A; e1A.u = u32x4{ejbA, ekb0, 0u, 0u};
            ABu e1B; e1B.u = u32x4{ejbB, ekb1, 0u, 0u};

            // two independent layer-1 chains
            f32x16 d1a = dc.v;
            d1a = __builtin_amdgcn_mfma_f32_32x32x16_bf16(wj0.s, e0A.s, d1a, 0, 0, 0);
            d1a = __builtin_amdgcn_mfma_f32_32x32x16_bf16(wj1.s, e1A.s, d1a, 0, 0, 0);
            f32x16 d1b = dc.v;
            d1b = __builtin_amdgcn_mfma_f32_32x32x16_bf16(wj0.s, e0B.s, d1b, 0, 0, 0);
            d1b = __builtin_amdgcn_mfma_f32_32x32x16_bf16(wj1.s, e1B.s, d1b, 0, 0, 0);

            const float wp = out_w[p];                 // shared (scalar)
            const f32x2 wp2 = {wp, wp};
            const f32x2 z2 = {};

            // finish half 0
            {
                D16 t; t.v = d1a;
                ABu hf0, hf1;
                hf0.w[0] = pk_relu(pack_trunc(t.q[0].x, t.q[0].y));
                hf0.w[1] = pk_relu(pack_trunc(t.q[0].z, t.q[0].w));
                hf0.w[2] = pk_relu(pack_trunc(t.q[1].x, t.q[1].y));
                hf0.w[3] = pk_relu(pack_trunc(t.q[1].z, t.q[1].w));
                hf1.w[0] = pk_relu(pack_trunc(t.q[2].x, t.q[2].y));
                hf1.w[1] = pk_relu(pack_trunc(t.q[2].z, t.q[2].w));
                hf1.w[2] = pk_relu(pack_trunc(t.q[3].x, t.q[3].y));
                hf1.w[3] = pk_relu(pack_trunc(t.q[3].z, t.q[3].w));
                f32x16 d2 = {};
                d2 = __builtin_amdgcn_mfma_f32_32x32x16_bf16(bf0.s, hf0.s, d2, 0, 0, 0);
                d2 = __builtin_amdgcn_mfma_f32_32x32x16_bf16(bf1.s, hf1.s, d2, 0, 0, 0);
                D16 r2; r2.v = d2;
                #pragma unroll
                for (int h = 0; h < 6; ++h) {
                    const f32x2 rr = __builtin_elementwise_max(r2.d[h], z2);
                    accA.d[h] = __builtin_elementwise_fma(rr, wp2, accA.d[h]);
                }
            }
            // finish half 1
            {
                D16 t; t.v = d1b;
                ABu hf0, hf1;
                hf0.w[0] = pk_relu(pack_trunc(t.q[0].x, t.q[0].y));
                hf0.w[1] = pk_relu(pack_trunc(t.q[0].z, t.q[0].w));
                hf0.w[2] = pk_relu(pack_trunc(t.q[1].x, t.q[1].y));
                hf0.w[3] = pk_relu(pack_trunc(t.q[1].z, t.q[1].w));
                hf1.w[0] = pk_relu(pack_trunc(t.q[2].x, t.q[2].y));
                hf1.w[1] = pk_relu(pack_trunc(t.q[2].z, t.q[2].w));
                hf1.w[2] = pk_relu(pack_trunc(t.q[3].x, t.q[3].y));
                hf1.w[3] = pk_relu(pack_trunc(t.q[3].z, t.q[3].w));
                f32x16 d2 = {};
                d2 = __builtin_amdgcn_mfma_f32_32x32x16_bf16(bf0.s, hf0.s, d2, 0, 0, 0);
                d2 = __builtin_amdgcn_mfma_f32_32x32x16_bf16(bf1.s, hf1.s, d2, 0, 0, 0);
                D16 r2; r2.v = d2;
                #pragma unroll
                for (int h = 0; h < 6; ++h) {
                    const f32x2 rr = __builtin_elementwise_max(r2.d[h], z2);
                    accB.d[h] = __builtin_elementwise_fma(rr, wp2, accB.d[h]);
                }
            }

            // advance j += 2 (p(j+2)-p(j) = 21-2j)
            p += 21 - 2 * j;
            j += 2;
            pj0A += e0step; pj0B += e0step;
            pj1A += e1step; pj1B += e1step;
        }
    }

    // ---- epilogue: eta[bb] = (1/6)*sum_r sW3[o_r]*acc[r], both halves ----
    float etaA = 0.0f, etaB = 0.0f;
    if (ihalf == 0) {       // r=0..11 -> o = 0..3, 8..11, 16..19
        #pragma unroll
        for (int r = 0; r < 12; ++r) {
            const float w3 = sW3[(r & 3) + 8 * (r >> 2)];
            etaA = fmaf(accA.f[r], w3, etaA);
            etaB = fmaf(accB.f[r], w3, etaB);
        }
    } else {                // r=0..7 -> o = 4..7, 12..15
        #pragma unroll
        for (int r = 0; r < 8; ++r) {
            const float w3 = sW3[(r & 3) + 8 * (r >> 2) + 4];
            etaA = fmaf(accA.f[r], w3, etaA);
            etaB = fmaf(accB.f[r], w3, etaB);
        }
    }
    etaA += __shfl_xor(etaA, 32, 64);   // combine o-halves
    etaB += __shfl_xor(etaB, 32, 64);
    if (ihalf == 0) {
        atomicAdd(&etab[b], etaA);
        atomicAdd(&etab[32 + b], etaB);
    }
    __syncthreads();

    if (tid < kMB) {
        float eta = etab[tid] * (1.0f / 6.0f) + etaC;
        eta = fminf(fmaxf(eta, -20.0f), 20.0f);
        const int ob = blockBase + tid;
        out[ob] = __expf(eta) * exposure[ob];
    }
}

extern "C" void kernel_launch(void* const* d_in, const int* in_sizes, int n_in,
                              void* d_out, int out_size, void* d_ws, size_t ws_size,
                              hipStream_t stream) {
    (void)n_in; (void)out_size; (void)d_ws; (void)ws_size;
    const float* x_cont     = (const float*)d_in[0];
    const int*   x_cat      = (const int*)  d_in[1];
    const float* exposure   = (const float*)d_in[2];
    const float* cont_W1    = (const float*)d_in[3];
    const float* cont_b1    = (const float*)d_in[4];
    const float* cont_W2    = (const float*)d_in[5];
    const float* cont_b2    = (const float*)d_in[6];
    const float* cat_tables = (const float*)d_in[7];
    const float* tokens     = (const float*)d_in[8];
    const float* sW1        = (const float*)d_in[9];
    const float* sb1        = (const float*)d_in[10];
    const float* sW2        = (const float*)d_in[11];
    const float* sb2        = (const float*)d_in[12];
    const float* sW3        = (const float*)d_in[13];
    const float* sb3        = (const float*)d_in[14];
    const float* out_w      = (const float*)d_in[15];
    const float* out_b      = (const float*)d_in[16];

    const int B = in_sizes[2];        // exposure is [B]
    pin_main<<<B / kMB, kBlock, 0, stream>>>(
        x_cont, x_cat, exposure, cont_W1, cont_b1, cont_W2, cont_b2,
        cat_tables, tokens, sW1, sb1, sW2, sb2, sW3, sb3, out_w, out_b,
        (float*)d_out);
}